// Round 1
// baseline (749.360 us; speedup 1.0000x reference)
//
#include <hip/hip_runtime.h>
#include <math.h>

#define B_  64
#define L_  512
#define S_  3
#define D_  128
#define OV_ 50000

__device__ __forceinline__ float waveReduceSum(float v) {
#pragma unroll
    for (int off = 32; off >= 1; off >>= 1) v += __shfl_xor(v, off, 64);
    return v;
}
__device__ __forceinline__ float waveReduceMax(float v) {
#pragma unroll
    for (int off = 32; off >= 1; off >>= 1) v = fmaxf(v, __shfl_xor(v, off, 64));
    return v;
}

// monotonic float -> uint encoding for atomicMax (compare as unsigned)
__device__ __forceinline__ unsigned int encf(float f) {
    unsigned int u = __float_as_uint(f);
    return (u & 0x80000000u) ? ~u : (u | 0x80000000u);
}
__device__ __forceinline__ float decf(unsigned int u) {
    unsigned int b = (u & 0x80000000u) ? (u ^ 0x80000000u) : ~u;
    return __uint_as_float(b);
}

// ---------------------------------------------------------------------------
// Kernel 1: per-batch attention -> hidden[b][128]; also inits rowmax/rowsum.
// 64 blocks x 256 threads. wave w handles words l = w, w+4, ...  Lane i owns
// dims 2i, 2i+1 (float2 per embedding row).
// ---------------------------------------------------------------------------
__global__ __launch_bounds__(256) void attn_kernel(
    const int* __restrict__ inputs, const float* __restrict__ lw,
    const int* __restrict__ mask, const float* __restrict__ emb,
    const float* __restrict__ Wa, const float* __restrict__ ba,
    float* __restrict__ hidden, unsigned int* __restrict__ rowmax,
    float* __restrict__ rowsum)
{
    const int b    = blockIdx.x;
    const int tid  = threadIdx.x;
    const int wave = tid >> 6;
    const int lane = tid & 63;

    if (tid == 0) { rowmax[b] = 0u; rowsum[b] = 0.0f; }

    __shared__ float s_imp[L_];
    __shared__ float s_part[4][D_];
    __shared__ float s_ctx[D_];
    __shared__ float s_red[4];

    const int* in_b = inputs + b * (L_ * S_);
    const float wa0 = Wa[2 * lane];
    const float wa1 = Wa[2 * lane + 1];
    const float babias = ba[0];

    // ---- Pass 1: word_imp[l] = mean_s(E[idx]) . W_attn + b, masked ----
    for (int l = wave; l < L_; l += 4) {
        float mx = 0.f, my = 0.f;
#pragma unroll
        for (int s = 0; s < S_; ++s) {
            int idx = in_b[l * S_ + s];
            if (idx != 0) {
                float2 e = ((const float2*)(emb + (long)idx * D_))[lane];
                mx += e.x; my += e.y;
            }
        }
        float tot = waveReduceSum(mx * wa0 + my * wa1);
        if (lane == 0) {
            float imp = tot * (1.0f / 3.0f) + babias;
            s_imp[l] = mask[b * L_ + l] ? -INFINITY : imp;
        }
    }
    __syncthreads();

    // ---- Pass 2: softmax over 512 words (in LDS) ----
    float v0 = s_imp[tid];
    float v1 = s_imp[tid + 256];
    float m = waveReduceMax(fmaxf(v0, v1));
    if (lane == 0) s_red[wave] = m;
    __syncthreads();
    m = fmaxf(fmaxf(s_red[0], s_red[1]), fmaxf(s_red[2], s_red[3]));
    __syncthreads();
    float p0 = expf(v0 - m);
    float p1 = expf(v1 - m);
    float ssum = waveReduceSum(p0 + p1);
    if (lane == 0) s_red[wave] = ssum;
    __syncthreads();
    float inv = 1.0f / (s_red[0] + s_red[1] + s_red[2] + s_red[3]);
    s_imp[tid] = p0 * inv;
    s_imp[tid + 256] = p1 * inv;
    __syncthreads();

    // ---- Pass 3: context[d] = sum_l ww[l] * mean_l[d] ----
    float cx = 0.f, cy = 0.f;
    for (int l = wave; l < L_; l += 4) {
        float mx = 0.f, my = 0.f;
#pragma unroll
        for (int s = 0; s < S_; ++s) {
            int idx = in_b[l * S_ + s];
            if (idx != 0) {
                float2 e = ((const float2*)(emb + (long)idx * D_))[lane];
                mx += e.x; my += e.y;
            }
        }
        float w = s_imp[l] * (1.0f / 3.0f);
        cx += w * mx; cy += w * my;
    }
    s_part[wave][2 * lane]     = cx;
    s_part[wave][2 * lane + 1] = cy;
    __syncthreads();
    if (tid < D_)
        s_ctx[tid] = s_part[0][tid] + s_part[1][tid] + s_part[2][tid] + s_part[3][tid];
    __syncthreads();

    // ---- Pass 4: sense softmax + hidden accumulation ----
    float hx = 0.f, hy = 0.f;
    const float lwb = lw[b];
    const float c0 = s_ctx[2 * lane];
    const float c1 = s_ctx[2 * lane + 1];
    for (int l = wave; l < L_; l += 4) {
        float ex[S_], ey[S_];
        int   id[S_];
#pragma unroll
        for (int s = 0; s < S_; ++s) {
            id[s] = in_b[l * S_ + s];
            if (id[s] != 0) {
                float2 e = ((const float2*)(emb + (long)id[s] * D_))[lane];
                ex[s] = e.x; ey[s] = e.y;
            } else { ex[s] = 0.f; ey[s] = 0.f; }
        }
        float s0 = waveReduceSum(ex[0] * c0 + ey[0] * c1);
        float s1 = waveReduceSum(ex[1] * c0 + ey[1] * c1);
        float s2 = waveReduceSum(ex[2] * c0 + ey[2] * c1);
        float mm = fmaxf(s0, fmaxf(s1, s2));
        float e0 = expf(s0 - mm), e1 = expf(s1 - mm), e2 = expf(s2 - mm);
        float f = lwb / (e0 + e1 + e2);
        float w0 = (id[0] != 0) ? e0 * f : 0.f;
        float w1 = (id[1] != 0) ? e1 * f : 0.f;
        float w2 = (id[2] != 0) ? e2 * f : 0.f;
        hx += w0 * ex[0] + w1 * ex[1] + w2 * ex[2];
        hy += w0 * ey[0] + w1 * ey[1] + w2 * ey[2];
    }
    s_part[wave][2 * lane]     = hx;
    s_part[wave][2 * lane + 1] = hy;
    __syncthreads();
    if (tid < D_)
        hidden[b * D_ + tid] = s_part[0][tid] + s_part[1][tid] + s_part[2][tid] + s_part[3][tid];
}

// ---------------------------------------------------------------------------
// Kernel 2: logits[b][v] = hidden[b] . W_lin[v] + b_lin[v], + per-row atomicMax.
// 391 blocks x 256 threads; block covers all 64 rows x 128 cols.
// thread: colgroup g = tid&31 (4 cols), rowgroup rg = tid>>5 (8 rows).
// ---------------------------------------------------------------------------
__global__ __launch_bounds__(256) void logits_kernel(
    const float* __restrict__ hidden, const float* __restrict__ Wl,
    const float* __restrict__ bl, float* __restrict__ logits,
    unsigned int* __restrict__ rowmax)
{
    __shared__ float s_hid[B_][D_];
    const int tid = threadIdx.x;

    const float4* hsrc = (const float4*)hidden;
    float4* hdst = (float4*)&s_hid[0][0];
#pragma unroll
    for (int i = 0; i < 8; ++i) hdst[tid + 256 * i] = hsrc[tid + 256 * i];
    __syncthreads();

    const int g  = tid & 31;
    const int rg = tid >> 5;
    const int vbase = blockIdx.x * 128;
    const int v0 = vbase + 4 * g;
    const bool valid = (v0 < OV_);   // OV_ % 4 == 0, so all-or-none per thread
    const int r0 = rg * 8;

    float acc[8][4];
#pragma unroll
    for (int i = 0; i < 8; ++i)
#pragma unroll
        for (int c = 0; c < 4; ++c) acc[i][c] = 0.f;

    const float4* wrow[4];
#pragma unroll
    for (int c = 0; c < 4; ++c)
        wrow[c] = (const float4*)(Wl + (long)(valid ? (v0 + c) : 0) * D_);

    for (int k4 = 0; k4 < D_ / 4; ++k4) {
        float4 w[4];
#pragma unroll
        for (int c = 0; c < 4; ++c) w[c] = wrow[c][k4];
#pragma unroll
        for (int i = 0; i < 8; ++i) {
            float4 h = ((const float4*)s_hid[r0 + i])[k4];
#pragma unroll
            for (int c = 0; c < 4; ++c)
                acc[i][c] += h.x * w[c].x + h.y * w[c].y + h.z * w[c].z + h.w * w[c].w;
        }
    }

    float4 bias = valid ? ((const float4*)bl)[v0 / 4] : make_float4(0.f, 0.f, 0.f, 0.f);
#pragma unroll
    for (int i = 0; i < 8; ++i) {
        acc[i][0] += bias.x; acc[i][1] += bias.y;
        acc[i][2] += bias.z; acc[i][3] += bias.w;

        if (valid) {
            float4 o = make_float4(acc[i][0], acc[i][1], acc[i][2], acc[i][3]);
            *((float4*)(logits + (long)(r0 + i) * OV_ + v0)) = o;
        }
        float mrow = valid
            ? fmaxf(fmaxf(acc[i][0], acc[i][1]), fmaxf(acc[i][2], acc[i][3]))
            : -INFINITY;
#pragma unroll
        for (int off = 16; off >= 1; off >>= 1)
            mrow = fmaxf(mrow, __shfl_xor(mrow, off, 64));
        if (g == 0) atomicMax(&rowmax[r0 + i], encf(mrow));
    }
}

// ---------------------------------------------------------------------------
// Kernel 3: rowsum[b] += sum_v exp(logit - rowmax[b]); 512 blocks (8 per row).
// ---------------------------------------------------------------------------
__global__ __launch_bounds__(256) void sumexp_kernel(
    const float* __restrict__ logits, const unsigned int* __restrict__ rowmax,
    float* __restrict__ rowsum)
{
    const int b     = blockIdx.x >> 3;
    const int chunk = blockIdx.x & 7;
    const float m = decf(rowmax[b]);
    const float* row = logits + (long)b * OV_;
    const int begin = chunk * (OV_ / 8);
    const int end   = begin + (OV_ / 8);

    float s = 0.f;
    for (int i = begin + threadIdx.x; i < end; i += 256) s += expf(row[i] - m);

    __shared__ float s_red[4];
    s = waveReduceSum(s);
    const int wave = threadIdx.x >> 6, lane = threadIdx.x & 63;
    if (lane == 0) s_red[wave] = s;
    __syncthreads();
    if (threadIdx.x == 0)
        atomicAdd(&rowsum[b], s_red[0] + s_red[1] + s_red[2] + s_red[3]);
}

// ---------------------------------------------------------------------------
// Kernel 4: out = logit - max - log(sum); float4 grid-stride (exact cover).
// ---------------------------------------------------------------------------
__global__ __launch_bounds__(256) void finalize_kernel(
    const float* __restrict__ logits, const unsigned int* __restrict__ rowmax,
    const float* __restrict__ rowsum, float* __restrict__ out)
{
    const long i4 = (long)blockIdx.x * 256 + threadIdx.x;   // float4 index
    const long e  = i4 * 4;                                  // element index
    const int b = (int)(e / OV_);                            // row uniform per float4
    const float m  = decf(rowmax[b]);
    const float lg = logf(rowsum[b]);
    float4 x = ((const float4*)logits)[i4];
    x.x = x.x - m - lg; x.y = x.y - m - lg;
    x.z = x.z - m - lg; x.w = x.w - m - lg;
    ((float4*)out)[i4] = x;
}

extern "C" void kernel_launch(void* const* d_in, const int* in_sizes, int n_in,
                              void* d_out, int out_size, void* d_ws, size_t ws_size,
                              hipStream_t stream) {
    const int*   inputs = (const int*)d_in[0];
    const float* lw     = (const float*)d_in[1];
    const int*   mask   = (const int*)d_in[2];
    const float* emb    = (const float*)d_in[3];
    const float* Wa     = (const float*)d_in[4];
    const float* ba     = (const float*)d_in[5];
    const float* Wl     = (const float*)d_in[6];
    const float* bl     = (const float*)d_in[7];
    float* out = (float*)d_out;

    float* ws = (float*)d_ws;
    float*        hidden = ws;                         // 8192 floats
    unsigned int* rowmax = (unsigned int*)(ws + 8192); // 64
    float*        rowsum = ws + 8256;                  // 64
    float*        logits = ws + 8320;                  // 64*50000

    attn_kernel<<<B_, 256, 0, stream>>>(inputs, lw, mask, emb, Wa, ba,
                                        hidden, rowmax, rowsum);
    logits_kernel<<<(OV_ + 127) / 128, 256, 0, stream>>>(hidden, Wl, bl,
                                                         logits, rowmax);
    sumexp_kernel<<<B_ * 8, 256, 0, stream>>>(logits, rowmax, rowsum);
    finalize_kernel<<<(B_ * OV_) / (4 * 256), 256, 0, stream>>>(logits, rowmax,
                                                                rowsum, out);
}

// Round 2
// 266.771 us; speedup vs baseline: 2.8090x; 2.8090x over previous
//
#include <hip/hip_runtime.h>
#include <math.h>

#define B_    64
#define L_    512
#define S_    3
#define D_    128
#define OV_   50000
#define VOC_  100000

__device__ __forceinline__ float waveReduceSum(float v) {
#pragma unroll
    for (int off = 32; off >= 1; off >>= 1) v += __shfl_xor(v, off, 64);
    return v;
}

// monotonic float -> uint encoding for atomicMax (compare as unsigned)
__device__ __forceinline__ unsigned int encf(float f) {
    unsigned int u = __float_as_uint(f);
    return (u & 0x80000000u) ? ~u : (u | 0x80000000u);
}
__device__ __forceinline__ float decf(unsigned int u) {
    unsigned int b = (u & 0x80000000u) ? (u ^ 0x80000000u) : ~u;
    return __uint_as_float(b);
}

// ---------------------------------------------------------------------------
// K0: P[v] = E[v] . W_attn  (streamed over the whole vocab).
// 625 blocks x 256 thr. Wave handles 2 rows/iter: lane = 32*h + j,
// h = row parity, j covers 128 dims as float4. 5-stage shuffle reduce per 32.
// ---------------------------------------------------------------------------
__global__ __launch_bounds__(256) void prequery_kernel(
    const float* __restrict__ emb, const float* __restrict__ Wa,
    float* __restrict__ P)
{
    const int lane = threadIdx.x & 63;
    const int h    = lane >> 5;          // 0/1 = which row of the pair
    const int j    = lane & 31;          // float4 index into 128 dims
    const int waveg = (blockIdx.x * 4) + (threadIdx.x >> 6);
    const int nwaves = gridDim.x * 4;

    const float4 wa = ((const float4*)Wa)[j];

    for (int r = waveg * 2; r < VOC_; r += nwaves * 2) {
        const float4 e = ((const float4*)(emb + (long)(r + h) * D_))[j];
        float s = e.x * wa.x + e.y * wa.y + e.z * wa.z + e.w * wa.w;
#pragma unroll
        for (int off = 16; off >= 1; off >>= 1) s += __shfl_xor(s, off, 64);
        if (j == 0) P[r + h] = s;
    }
}

// ---------------------------------------------------------------------------
// K1: word_imp via P-gather -> masked softmax over 512 words -> w[b][l].
// Also zeroes context/hidden and inits rowmax/rowsum. 64 blocks x 256 thr.
// ---------------------------------------------------------------------------
__global__ __launch_bounds__(256) void wordsoftmax_kernel(
    const int* __restrict__ inputs, const int* __restrict__ mask,
    const float* __restrict__ P, const float* __restrict__ ba,
    float* __restrict__ wword, float* __restrict__ context,
    float* __restrict__ hidden, unsigned int* __restrict__ rowmax,
    float* __restrict__ rowsum)
{
    const int b   = blockIdx.x;
    const int tid = threadIdx.x;
    const int wave = tid >> 6, lane = tid & 63;

    if (tid == 0) { rowmax[b] = 0u; rowsum[b] = 0.0f; }
    if (tid < D_) { context[b * D_ + tid] = 0.f; hidden[b * D_ + tid] = 0.f; }

    __shared__ float s_imp[L_];
    __shared__ float s_red[4];

    const int* in_b = inputs + b * (L_ * S_);
    const float babias = ba[0];

#pragma unroll
    for (int half = 0; half < 2; ++half) {
        const int l = tid + half * 256;
        float acc = 0.f;
#pragma unroll
        for (int s = 0; s < S_; ++s) {
            int idx = in_b[l * S_ + s];
            if (idx != 0) acc += P[idx];
        }
        float imp = acc * (1.0f / 3.0f) + babias;
        s_imp[l] = mask[b * L_ + l] ? -INFINITY : imp;
    }
    __syncthreads();

    float v0 = s_imp[tid], v1 = s_imp[tid + 256];
    float m = fmaxf(v0, v1);
#pragma unroll
    for (int off = 32; off >= 1; off >>= 1) m = fmaxf(m, __shfl_xor(m, off, 64));
    if (lane == 0) s_red[wave] = m;
    __syncthreads();
    m = fmaxf(fmaxf(s_red[0], s_red[1]), fmaxf(s_red[2], s_red[3]));
    __syncthreads();
    float p0 = expf(v0 - m), p1 = expf(v1 - m);
    float ssum = waveReduceSum(p0 + p1);
    if (lane == 0) s_red[wave] = ssum;
    __syncthreads();
    float inv = 1.0f / (s_red[0] + s_red[1] + s_red[2] + s_red[3]);
    wword[b * L_ + tid]       = p0 * inv;
    wword[b * L_ + tid + 256] = p1 * inv;
}

// ---------------------------------------------------------------------------
// K2: context[b][d] += sum over this block's 64 words of w_l/3 * sum_s E[idx].
// Grid B*8 = 512 blocks x 256 thr. No cross-lane reductions: gather+fma only.
// ---------------------------------------------------------------------------
__global__ __launch_bounds__(256) void context_kernel(
    const int* __restrict__ inputs, const float* __restrict__ wword,
    const float* __restrict__ emb, float* __restrict__ context)
{
    const int b     = blockIdx.x >> 3;
    const int base  = (blockIdx.x & 7) * 64;     // first word of this chunk
    const int tid   = threadIdx.x;
    const int wave  = tid >> 6, lane = tid & 63;

    __shared__ float s_w[64];
    __shared__ float s_part[4][D_];

    if (tid < 64) s_w[tid] = wword[b * L_ + base + tid] * (1.0f / 3.0f);
    __syncthreads();

    const int* in_b = inputs + b * (L_ * S_);
    float cx = 0.f, cy = 0.f;

    for (int lw = wave; lw < 64; lw += 4) {
        const int l = base + lw;
        const float w = s_w[lw];
        float mx = 0.f, my = 0.f;
#pragma unroll
        for (int s = 0; s < S_; ++s) {
            int idx = in_b[l * S_ + s];
            if (idx != 0) {
                float2 e = ((const float2*)(emb + (long)idx * D_))[lane];
                mx += e.x; my += e.y;
            }
        }
        cx += w * mx; cy += w * my;
    }
    s_part[wave][2 * lane]     = cx;
    s_part[wave][2 * lane + 1] = cy;
    __syncthreads();
    if (tid < D_)
        atomicAdd(&context[b * D_ + tid],
                  s_part[0][tid] + s_part[1][tid] + s_part[2][tid] + s_part[3][tid]);
}

// ---------------------------------------------------------------------------
// K3: sense softmax + hidden accumulation. Grid B*8 blocks x 256 thr.
// ---------------------------------------------------------------------------
__global__ __launch_bounds__(256) void sense_kernel(
    const int* __restrict__ inputs, const float* __restrict__ lw,
    const float* __restrict__ context, const float* __restrict__ emb,
    float* __restrict__ hidden)
{
    const int b     = blockIdx.x >> 3;
    const int base  = (blockIdx.x & 7) * 64;
    const int tid   = threadIdx.x;
    const int wave  = tid >> 6, lane = tid & 63;

    __shared__ float s_part[4][D_];

    const int* in_b = inputs + b * (L_ * S_);
    const float lwb = lw[b];
    const float c0 = context[b * D_ + 2 * lane];
    const float c1 = context[b * D_ + 2 * lane + 1];

    float hx = 0.f, hy = 0.f;
    for (int lw_ = wave; lw_ < 64; lw_ += 4) {
        const int l = base + lw_;
        float ex[S_], ey[S_];
        int   id[S_];
#pragma unroll
        for (int s = 0; s < S_; ++s) {
            id[s] = in_b[l * S_ + s];
            if (id[s] != 0) {
                float2 e = ((const float2*)(emb + (long)id[s] * D_))[lane];
                ex[s] = e.x; ey[s] = e.y;
            } else { ex[s] = 0.f; ey[s] = 0.f; }
        }
        float s0 = waveReduceSum(ex[0] * c0 + ey[0] * c1);
        float s1 = waveReduceSum(ex[1] * c0 + ey[1] * c1);
        float s2 = waveReduceSum(ex[2] * c0 + ey[2] * c1);
        float mm = fmaxf(s0, fmaxf(s1, s2));
        float e0 = expf(s0 - mm), e1 = expf(s1 - mm), e2 = expf(s2 - mm);
        float f = lwb / (e0 + e1 + e2);
        float w0 = (id[0] != 0) ? e0 * f : 0.f;
        float w1 = (id[1] != 0) ? e1 * f : 0.f;
        float w2 = (id[2] != 0) ? e2 * f : 0.f;
        hx += w0 * ex[0] + w1 * ex[1] + w2 * ex[2];
        hy += w0 * ey[0] + w1 * ey[1] + w2 * ey[2];
    }
    s_part[wave][2 * lane]     = hx;
    s_part[wave][2 * lane + 1] = hy;
    __syncthreads();
    if (tid < D_)
        atomicAdd(&hidden[b * D_ + tid],
                  s_part[0][tid] + s_part[1][tid] + s_part[2][tid] + s_part[3][tid]);
}

// ---------------------------------------------------------------------------
// K4: logits[b][v] = hidden[b] . W_lin[v] + b_lin[v], + per-row atomicMax.
// ---------------------------------------------------------------------------
__global__ __launch_bounds__(256) void logits_kernel(
    const float* __restrict__ hidden, const float* __restrict__ Wl,
    const float* __restrict__ bl, float* __restrict__ logits,
    unsigned int* __restrict__ rowmax)
{
    __shared__ float s_hid[B_][D_];
    const int tid = threadIdx.x;

    const float4* hsrc = (const float4*)hidden;
    float4* hdst = (float4*)&s_hid[0][0];
#pragma unroll
    for (int i = 0; i < 8; ++i) hdst[tid + 256 * i] = hsrc[tid + 256 * i];
    __syncthreads();

    const int g  = tid & 31;
    const int rg = tid >> 5;
    const int v0 = blockIdx.x * 128 + 4 * g;
    const bool valid = (v0 < OV_);
    const int r0 = rg * 8;

    float acc[8][4];
#pragma unroll
    for (int i = 0; i < 8; ++i)
#pragma unroll
        for (int c = 0; c < 4; ++c) acc[i][c] = 0.f;

    const float4* wrow[4];
#pragma unroll
    for (int c = 0; c < 4; ++c)
        wrow[c] = (const float4*)(Wl + (long)(valid ? (v0 + c) : 0) * D_);

    for (int k4 = 0; k4 < D_ / 4; ++k4) {
        float4 w[4];
#pragma unroll
        for (int c = 0; c < 4; ++c) w[c] = wrow[c][k4];
#pragma unroll
        for (int i = 0; i < 8; ++i) {
            float4 h = ((const float4*)s_hid[r0 + i])[k4];
#pragma unroll
            for (int c = 0; c < 4; ++c)
                acc[i][c] += h.x * w[c].x + h.y * w[c].y + h.z * w[c].z + h.w * w[c].w;
        }
    }

    float4 bias = valid ? ((const float4*)bl)[v0 / 4] : make_float4(0.f, 0.f, 0.f, 0.f);
#pragma unroll
    for (int i = 0; i < 8; ++i) {
        acc[i][0] += bias.x; acc[i][1] += bias.y;
        acc[i][2] += bias.z; acc[i][3] += bias.w;
        if (valid) {
            float4 o = make_float4(acc[i][0], acc[i][1], acc[i][2], acc[i][3]);
            *((float4*)(logits + (long)(r0 + i) * OV_ + v0)) = o;
        }
        float mrow = valid
            ? fmaxf(fmaxf(acc[i][0], acc[i][1]), fmaxf(acc[i][2], acc[i][3]))
            : -INFINITY;
#pragma unroll
        for (int off = 16; off >= 1; off >>= 1)
            mrow = fmaxf(mrow, __shfl_xor(mrow, off, 64));
        if (g == 0) atomicMax(&rowmax[r0 + i], encf(mrow));
    }
}

// ---------------------------------------------------------------------------
// K5: rowsum[b] += sum_v exp(logit - rowmax[b]); 4 blocks per row, float4.
// ---------------------------------------------------------------------------
__global__ __launch_bounds__(256) void sumexp_kernel(
    const float* __restrict__ logits, const unsigned int* __restrict__ rowmax,
    float* __restrict__ rowsum)
{
    const int b     = blockIdx.x >> 2;
    const int chunk = blockIdx.x & 3;
    const float m = decf(rowmax[b]);
    const float4* row = (const float4*)(logits + (long)b * OV_);
    const int begin = chunk * (OV_ / 16);        // 3125 float4 per chunk
    const int end   = begin + (OV_ / 16);

    float s = 0.f;
    for (int i = begin + threadIdx.x; i < end; i += 256) {
        float4 x = row[i];
        s += expf(x.x - m) + expf(x.y - m) + expf(x.z - m) + expf(x.w - m);
    }

    __shared__ float s_red[4];
    s = waveReduceSum(s);
    const int wave = threadIdx.x >> 6, lane = threadIdx.x & 63;
    if (lane == 0) s_red[wave] = s;
    __syncthreads();
    if (threadIdx.x == 0)
        atomicAdd(&rowsum[b], s_red[0] + s_red[1] + s_red[2] + s_red[3]);
}

// ---------------------------------------------------------------------------
// K6: out = logit - max - log(sum); float4, exact cover.
// ---------------------------------------------------------------------------
__global__ __launch_bounds__(256) void finalize_kernel(
    const float* __restrict__ logits, const unsigned int* __restrict__ rowmax,
    const float* __restrict__ rowsum, float* __restrict__ out)
{
    const long i4 = (long)blockIdx.x * 256 + threadIdx.x;
    const long e  = i4 * 4;
    const int b = (int)(e / OV_);
    const float m  = decf(rowmax[b]);
    const float lg = logf(rowsum[b]);
    float4 x = ((const float4*)logits)[i4];
    x.x = x.x - m - lg; x.y = x.y - m - lg;
    x.z = x.z - m - lg; x.w = x.w - m - lg;
    ((float4*)out)[i4] = x;
}

extern "C" void kernel_launch(void* const* d_in, const int* in_sizes, int n_in,
                              void* d_out, int out_size, void* d_ws, size_t ws_size,
                              hipStream_t stream) {
    const int*   inputs = (const int*)d_in[0];
    const float* lw     = (const float*)d_in[1];
    const int*   mask   = (const int*)d_in[2];
    const float* emb    = (const float*)d_in[3];
    const float* Wa     = (const float*)d_in[4];
    const float* ba     = (const float*)d_in[5];
    const float* Wl     = (const float*)d_in[6];
    const float* bl     = (const float*)d_in[7];
    float* out = (float*)d_out;

    float* ws = (float*)d_ws;
    float*        hidden  = ws;                          // 8192
    unsigned int* rowmax  = (unsigned int*)(ws + 8192);  // 64
    float*        rowsum  = ws + 8256;                   // 64
    float*        logits  = ws + 8320;                   // 3,200,000
    float*        P       = ws + 8320 + 3200000;         // 100,000
    float*        wword   = P + VOC_;                    // 32,768
    float*        context = wword + B_ * L_;             // 8,192

    prequery_kernel<<<625, 256, 0, stream>>>(emb, Wa, P);
    wordsoftmax_kernel<<<B_, 256, 0, stream>>>(inputs, mask, P, ba, wword,
                                               context, hidden, rowmax, rowsum);
    context_kernel<<<B_ * 8, 256, 0, stream>>>(inputs, wword, emb, context);
    sense_kernel<<<B_ * 8, 256, 0, stream>>>(inputs, lw, context, emb, hidden);
    logits_kernel<<<(OV_ + 127) / 128, 256, 0, stream>>>(hidden, Wl, bl,
                                                         logits, rowmax);
    sumexp_kernel<<<B_ * 4, 256, 0, stream>>>(logits, rowmax, rowsum);
    finalize_kernel<<<(B_ * OV_) / (4 * 256), 256, 0, stream>>>(logits, rowmax,
                                                                rowsum, out);
}

// Round 3
// 224.452 us; speedup vs baseline: 3.3386x; 1.1885x over previous
//
#include <hip/hip_runtime.h>
#include <math.h>

#define B_    64
#define L_    512
#define S_    3
#define D_    128
#define OV_   50000
#define VOC_  100000

typedef __attribute__((ext_vector_type(8))) short bf16x8;
typedef __attribute__((ext_vector_type(4))) float f32x4;

__device__ __forceinline__ float waveReduceSum(float v) {
#pragma unroll
    for (int off = 32; off >= 1; off >>= 1) v += __shfl_xor(v, off, 64);
    return v;
}
__device__ __forceinline__ float waveReduceMax(float v) {
#pragma unroll
    for (int off = 32; off >= 1; off >>= 1) v = fmaxf(v, __shfl_xor(v, off, 64));
    return v;
}

// fp32 -> bf16 round-to-nearest-even
__device__ __forceinline__ short f2bf(float f) {
    unsigned int u = __float_as_uint(f);
    return (short)((u + 0x7FFFu + ((u >> 16) & 1u)) >> 16);
}

// ---------------------------------------------------------------------------
// K0: P[v] = E[v] . W_attn  (streamed over the whole vocab).
// ---------------------------------------------------------------------------
__global__ __launch_bounds__(256) void prequery_kernel(
    const float* __restrict__ emb, const float* __restrict__ Wa,
    float* __restrict__ P)
{
    const int lane = threadIdx.x & 63;
    const int h    = lane >> 5;
    const int j    = lane & 31;
    const int waveg = (blockIdx.x * 4) + (threadIdx.x >> 6);
    const int nwaves = gridDim.x * 4;

    const float4 wa = ((const float4*)Wa)[j];

    for (int r = waveg * 2; r < VOC_; r += nwaves * 2) {
        const float4 e = ((const float4*)(emb + (long)(r + h) * D_))[j];
        float s = e.x * wa.x + e.y * wa.y + e.z * wa.z + e.w * wa.w;
#pragma unroll
        for (int off = 16; off >= 1; off >>= 1) s += __shfl_xor(s, off, 64);
        if (j == 0) P[r + h] = s;
    }
}

// ---------------------------------------------------------------------------
// K1: word_imp via P-gather -> masked softmax over 512 words -> w[b][l].
// Also zeroes context/hidden. 64 blocks x 256 thr.
// ---------------------------------------------------------------------------
__global__ __launch_bounds__(256) void wordsoftmax_kernel(
    const int* __restrict__ inputs, const int* __restrict__ mask,
    const float* __restrict__ P, const float* __restrict__ ba,
    float* __restrict__ wword, float* __restrict__ context,
    float* __restrict__ hidden)
{
    const int b   = blockIdx.x;
    const int tid = threadIdx.x;
    const int wave = tid >> 6, lane = tid & 63;

    if (tid < D_) { context[b * D_ + tid] = 0.f; hidden[b * D_ + tid] = 0.f; }

    __shared__ float s_imp[L_];
    __shared__ float s_red[4];

    const int* in_b = inputs + b * (L_ * S_);
    const float babias = ba[0];

#pragma unroll
    for (int half = 0; half < 2; ++half) {
        const int l = tid + half * 256;
        float acc = 0.f;
#pragma unroll
        for (int s = 0; s < S_; ++s) {
            int idx = in_b[l * S_ + s];
            if (idx != 0) acc += P[idx];
        }
        float imp = acc * (1.0f / 3.0f) + babias;
        s_imp[l] = mask[b * L_ + l] ? -INFINITY : imp;
    }
    __syncthreads();

    float v0 = s_imp[tid], v1 = s_imp[tid + 256];
    float m = waveReduceMax(fmaxf(v0, v1));
    if (lane == 0) s_red[wave] = m;
    __syncthreads();
    m = fmaxf(fmaxf(s_red[0], s_red[1]), fmaxf(s_red[2], s_red[3]));
    __syncthreads();
    float p0 = expf(v0 - m), p1 = expf(v1 - m);
    float ssum = waveReduceSum(p0 + p1);
    if (lane == 0) s_red[wave] = ssum;
    __syncthreads();
    float inv = 1.0f / (s_red[0] + s_red[1] + s_red[2] + s_red[3]);
    wword[b * L_ + tid]       = p0 * inv;
    wword[b * L_ + tid + 256] = p1 * inv;
}

// ---------------------------------------------------------------------------
// K2: context accumulation. Grid B*8 blocks x 256 thr.
// ---------------------------------------------------------------------------
__global__ __launch_bounds__(256) void context_kernel(
    const int* __restrict__ inputs, const float* __restrict__ wword,
    const float* __restrict__ emb, float* __restrict__ context)
{
    const int b     = blockIdx.x >> 3;
    const int base  = (blockIdx.x & 7) * 64;
    const int tid   = threadIdx.x;
    const int wave  = tid >> 6, lane = tid & 63;

    __shared__ float s_w[64];
    __shared__ float s_part[4][D_];

    if (tid < 64) s_w[tid] = wword[b * L_ + base + tid] * (1.0f / 3.0f);
    __syncthreads();

    const int* in_b = inputs + b * (L_ * S_);
    float cx = 0.f, cy = 0.f;

    for (int lw = wave; lw < 64; lw += 4) {
        const int l = base + lw;
        const float w = s_w[lw];
        float mx = 0.f, my = 0.f;
#pragma unroll
        for (int s = 0; s < S_; ++s) {
            int idx = in_b[l * S_ + s];
            if (idx != 0) {
                float2 e = ((const float2*)(emb + (long)idx * D_))[lane];
                mx += e.x; my += e.y;
            }
        }
        cx += w * mx; cy += w * my;
    }
    s_part[wave][2 * lane]     = cx;
    s_part[wave][2 * lane + 1] = cy;
    __syncthreads();
    if (tid < D_)
        atomicAdd(&context[b * D_ + tid],
                  s_part[0][tid] + s_part[1][tid] + s_part[2][tid] + s_part[3][tid]);
}

// ---------------------------------------------------------------------------
// K3: sense softmax + hidden accumulation. Grid B*8 blocks x 256 thr.
// ---------------------------------------------------------------------------
__global__ __launch_bounds__(256) void sense_kernel(
    const int* __restrict__ inputs, const float* __restrict__ lw,
    const float* __restrict__ context, const float* __restrict__ emb,
    float* __restrict__ hidden)
{
    const int b     = blockIdx.x >> 3;
    const int base  = (blockIdx.x & 7) * 64;
    const int tid   = threadIdx.x;
    const int wave  = tid >> 6, lane = tid & 63;

    __shared__ float s_part[4][D_];

    const int* in_b = inputs + b * (L_ * S_);
    const float lwb = lw[b];
    const float c0 = context[b * D_ + 2 * lane];
    const float c1 = context[b * D_ + 2 * lane + 1];

    float hx = 0.f, hy = 0.f;
    for (int lw_ = wave; lw_ < 64; lw_ += 4) {
        const int l = base + lw_;
        float ex[S_], ey[S_];
        int   id[S_];
#pragma unroll
        for (int s = 0; s < S_; ++s) {
            id[s] = in_b[l * S_ + s];
            if (id[s] != 0) {
                float2 e = ((const float2*)(emb + (long)id[s] * D_))[lane];
                ex[s] = e.x; ey[s] = e.y;
            } else { ex[s] = 0.f; ey[s] = 0.f; }
        }
        float s0 = waveReduceSum(ex[0] * c0 + ey[0] * c1);
        float s1 = waveReduceSum(ex[1] * c0 + ey[1] * c1);
        float s2 = waveReduceSum(ex[2] * c0 + ey[2] * c1);
        float mm = fmaxf(s0, fmaxf(s1, s2));
        float e0 = expf(s0 - mm), e1 = expf(s1 - mm), e2 = expf(s2 - mm);
        float f = lwb / (e0 + e1 + e2);
        float w0 = (id[0] != 0) ? e0 * f : 0.f;
        float w1 = (id[1] != 0) ? e1 * f : 0.f;
        float w2 = (id[2] != 0) ? e2 * f : 0.f;
        hx += w0 * ex[0] + w1 * ex[1] + w2 * ex[2];
        hy += w0 * ey[0] + w1 * ey[1] + w2 * ey[2];
    }
    s_part[wave][2 * lane]     = hx;
    s_part[wave][2 * lane + 1] = hy;
    __syncthreads();
    if (tid < D_)
        atomicAdd(&hidden[b * D_ + tid],
                  s_part[0][tid] + s_part[1][tid] + s_part[2][tid] + s_part[3][tid]);
}

// ---------------------------------------------------------------------------
// K4: logits via MFMA. 782 blocks x 256 thr (4 waves). Wave computes a
// 64(b) x 16(v) tile: A = hidden frags (regs, whole kernel), B = W_lin rows
// loaded fp32 coalesced-per-row, converted to bf16 in-register.
// Layouts (m89-verified): A[m=lane&15][k=quad*8+j]; B[k=quad*8+j][n=lane&15];
// D: col=lane&15, row=quad*4+reg.
// ---------------------------------------------------------------------------
__global__ __launch_bounds__(256) void logits_kernel(
    const float* __restrict__ hidden, const float* __restrict__ Wl,
    const float* __restrict__ bl, float* __restrict__ logits)
{
    const int tid  = threadIdx.x;
    const int wave = tid >> 6, lane = tid & 63;
    const int m15  = lane & 15, quad = lane >> 4;
    const int v    = blockIdx.x * 64 + wave * 16 + m15;
    const int vc   = (v < OV_) ? v : (OV_ - 1);

    // A fragments: 4 row-tiles x 4 k-steps, each 8 bf16 (k = ks*32 + quad*8 + j)
    bf16x8 afrag[4][4];
#pragma unroll
    for (int t = 0; t < 4; ++t) {
        const float* hrow = hidden + (t * 16 + m15) * D_ + quad * 8;
#pragma unroll
        for (int ks = 0; ks < 4; ++ks) {
            float4 x0 = *(const float4*)(hrow + ks * 32);
            float4 x1 = *(const float4*)(hrow + ks * 32 + 4);
            bf16x8 a;
            a[0] = f2bf(x0.x); a[1] = f2bf(x0.y); a[2] = f2bf(x0.z); a[3] = f2bf(x0.w);
            a[4] = f2bf(x1.x); a[5] = f2bf(x1.y); a[6] = f2bf(x1.z); a[7] = f2bf(x1.w);
            afrag[t][ks] = a;
        }
    }

    f32x4 acc[4];
#pragma unroll
    for (int t = 0; t < 4; ++t) acc[t] = (f32x4){0.f, 0.f, 0.f, 0.f};

    const float* wrow = Wl + (long)vc * D_ + quad * 8;
#pragma unroll
    for (int ks = 0; ks < 4; ++ks) {
        float4 x0 = *(const float4*)(wrow + ks * 32);
        float4 x1 = *(const float4*)(wrow + ks * 32 + 4);
        bf16x8 bfr;
        bfr[0] = f2bf(x0.x); bfr[1] = f2bf(x0.y); bfr[2] = f2bf(x0.z); bfr[3] = f2bf(x0.w);
        bfr[4] = f2bf(x1.x); bfr[5] = f2bf(x1.y); bfr[6] = f2bf(x1.z); bfr[7] = f2bf(x1.w);
#pragma unroll
        for (int t = 0; t < 4; ++t)
            acc[t] = __builtin_amdgcn_mfma_f32_16x16x32_bf16(afrag[t][ks], bfr,
                                                             acc[t], 0, 0, 0);
    }

    const float bias = bl[vc];
    if (v < OV_) {
#pragma unroll
        for (int t = 0; t < 4; ++t) {
#pragma unroll
            for (int r = 0; r < 4; ++r) {
                const int row = t * 16 + quad * 4 + r;
                logits[(long)row * OV_ + v] = acc[t][r] + bias;
            }
        }
    }
}

// ---------------------------------------------------------------------------
// K5: per-row max then sum(exp) — one block per row, two passes (L2-hot).
// ---------------------------------------------------------------------------
__global__ __launch_bounds__(256) void rowmaxsum_kernel(
    const float* __restrict__ logits, float* __restrict__ rowmax,
    float* __restrict__ rowsum)
{
    const int b = blockIdx.x;
    const float4* row = (const float4*)(logits + (long)b * OV_);
    const int n4 = OV_ / 4;  // 12500
    const int tid = threadIdx.x;
    const int wave = tid >> 6, lane = tid & 63;
    __shared__ float s_red[4];

    float m = -INFINITY;
    for (int i = tid; i < n4; i += 256) {
        float4 x = row[i];
        m = fmaxf(m, fmaxf(fmaxf(x.x, x.y), fmaxf(x.z, x.w)));
    }
    m = waveReduceMax(m);
    if (lane == 0) s_red[wave] = m;
    __syncthreads();
    m = fmaxf(fmaxf(s_red[0], s_red[1]), fmaxf(s_red[2], s_red[3]));
    __syncthreads();

    float s = 0.f;
    for (int i = tid; i < n4; i += 256) {
        float4 x = row[i];
        s += expf(x.x - m) + expf(x.y - m) + expf(x.z - m) + expf(x.w - m);
    }
    s = waveReduceSum(s);
    if (lane == 0) s_red[wave] = s;
    __syncthreads();
    if (tid == 0) {
        rowmax[b] = m;
        rowsum[b] = s_red[0] + s_red[1] + s_red[2] + s_red[3];
    }
}

// ---------------------------------------------------------------------------
// K6: out = logit - max - log(sum); float4, exact cover.
// ---------------------------------------------------------------------------
__global__ __launch_bounds__(256) void finalize_kernel(
    const float* __restrict__ logits, const float* __restrict__ rowmax,
    const float* __restrict__ rowsum, float* __restrict__ out)
{
    const long i4 = (long)blockIdx.x * 256 + threadIdx.x;
    const long e  = i4 * 4;
    const int b = (int)(e / OV_);
    const float m  = rowmax[b];
    const float lg = logf(rowsum[b]);
    float4 x = ((const float4*)logits)[i4];
    x.x = x.x - m - lg; x.y = x.y - m - lg;
    x.z = x.z - m - lg; x.w = x.w - m - lg;
    ((float4*)out)[i4] = x;
}

extern "C" void kernel_launch(void* const* d_in, const int* in_sizes, int n_in,
                              void* d_out, int out_size, void* d_ws, size_t ws_size,
                              hipStream_t stream) {
    const int*   inputs = (const int*)d_in[0];
    const float* lw     = (const float*)d_in[1];
    const int*   mask   = (const int*)d_in[2];
    const float* emb    = (const float*)d_in[3];
    const float* Wa     = (const float*)d_in[4];
    const float* ba     = (const float*)d_in[5];
    const float* Wl     = (const float*)d_in[6];
    const float* bl     = (const float*)d_in[7];
    float* out = (float*)d_out;

    float* ws = (float*)d_ws;
    float* hidden  = ws;                          // 8,192
    float* rowmax  = ws + 8192;                   // 64
    float* rowsum  = ws + 8256;                   // 64
    float* logits  = ws + 8320;                   // 3,200,000
    float* P       = ws + 8320 + 3200000;         // 100,000
    float* wword   = P + VOC_;                    // 32,768
    float* context = wword + B_ * L_;             // 8,192

    prequery_kernel<<<625, 256, 0, stream>>>(emb, Wa, P);
    wordsoftmax_kernel<<<B_, 256, 0, stream>>>(inputs, mask, P, ba, wword,
                                               context, hidden);
    context_kernel<<<B_ * 8, 256, 0, stream>>>(inputs, wword, emb, context);
    sense_kernel<<<B_ * 8, 256, 0, stream>>>(inputs, lw, context, emb, hidden);
    logits_kernel<<<(OV_ + 63) / 64, 256, 0, stream>>>(hidden, Wl, bl, logits);
    rowmaxsum_kernel<<<B_, 256, 0, stream>>>(logits, rowmax, rowsum);
    finalize_kernel<<<(B_ * OV_) / (4 * 256), 256, 0, stream>>>(logits, rowmax,
                                                                rowsum, out);
}

// Round 4
// 175.788 us; speedup vs baseline: 4.2629x; 1.2768x over previous
//
#include <hip/hip_runtime.h>
#include <math.h>

#define B_    64
#define L_    512
#define S_    3
#define D_    128
#define OV_   50000
#define VOC_  100000
#define NBLK_ 782   // ceil(OV_/64)

typedef __attribute__((ext_vector_type(8))) short bf16x8;
typedef __attribute__((ext_vector_type(4))) float f32x4;

__device__ __forceinline__ float waveReduceSum(float v) {
#pragma unroll
    for (int off = 32; off >= 1; off >>= 1) v += __shfl_xor(v, off, 64);
    return v;
}
__device__ __forceinline__ float waveReduceMax(float v) {
#pragma unroll
    for (int off = 32; off >= 1; off >>= 1) v = fmaxf(v, __shfl_xor(v, off, 64));
    return v;
}

// fp32 -> bf16 round-to-nearest-even
__device__ __forceinline__ short f2bf(float f) {
    unsigned int u = __float_as_uint(f);
    return (short)((u + 0x7FFFu + ((u >> 16) & 1u)) >> 16);
}

// ---------------------------------------------------------------------------
// K0: P[v] = E[v] . W_attn. 625 blocks. Lane: q=row-of-4, j=float8 chunk.
// 4 rows per wave-iter, 4-deep shuffle reduce (within 16 lanes).
// ---------------------------------------------------------------------------
__global__ __launch_bounds__(256) void prequery_kernel(
    const float* __restrict__ emb, const float* __restrict__ Wa,
    float* __restrict__ P)
{
    const int lane = threadIdx.x & 63;
    const int q = lane >> 4;            // which of 4 rows
    const int j = lane & 15;            // float8 chunk of 128 dims
    const int waveg = blockIdx.x * 4 + (threadIdx.x >> 6);
    const int nwaves = gridDim.x * 4;

    const float4 wa0 = ((const float4*)Wa)[2 * j];
    const float4 wa1 = ((const float4*)Wa)[2 * j + 1];

    for (int r0 = waveg * 4; r0 < VOC_; r0 += nwaves * 4) {
        const float4* row = (const float4*)(emb + (long)(r0 + q) * D_ + j * 8);
        float4 e0 = row[0], e1 = row[1];
        float s = e0.x * wa0.x + e0.y * wa0.y + e0.z * wa0.z + e0.w * wa0.w
                + e1.x * wa1.x + e1.y * wa1.y + e1.z * wa1.z + e1.w * wa1.w;
#pragma unroll
        for (int off = 8; off >= 1; off >>= 1) s += __shfl_xor(s, off, 64);
        if (j == 0) P[r0 + q] = s;
    }
}

// ---------------------------------------------------------------------------
// K1: word softmax from P-gathers; zeroes context/hidden. 64 blocks.
// ---------------------------------------------------------------------------
__global__ __launch_bounds__(256) void wordsoftmax_kernel(
    const int* __restrict__ inputs, const int* __restrict__ mask,
    const float* __restrict__ P, const float* __restrict__ ba,
    float* __restrict__ wword, float* __restrict__ context,
    float* __restrict__ hidden)
{
    const int b   = blockIdx.x;
    const int tid = threadIdx.x;
    const int wave = tid >> 6, lane = tid & 63;

    if (tid < D_) { context[b * D_ + tid] = 0.f; hidden[b * D_ + tid] = 0.f; }

    __shared__ float s_imp[L_];
    __shared__ float s_red[4];

    const int* in_b = inputs + b * (L_ * S_);
    const float babias = ba[0];

#pragma unroll
    for (int half = 0; half < 2; ++half) {
        const int l = tid + half * 256;
        float acc = 0.f;
#pragma unroll
        for (int s = 0; s < S_; ++s) {
            int idx = in_b[l * S_ + s];
            if (idx != 0) acc += P[idx];
        }
        float imp = acc * (1.0f / 3.0f) + babias;
        s_imp[l] = mask[b * L_ + l] ? -INFINITY : imp;
    }
    __syncthreads();

    float v0 = s_imp[tid], v1 = s_imp[tid + 256];
    float m = waveReduceMax(fmaxf(v0, v1));
    if (lane == 0) s_red[wave] = m;
    __syncthreads();
    m = fmaxf(fmaxf(s_red[0], s_red[1]), fmaxf(s_red[2], s_red[3]));
    __syncthreads();
    float p0 = expf(v0 - m), p1 = expf(v1 - m);
    float ssum = waveReduceSum(p0 + p1);
    if (lane == 0) s_red[wave] = ssum;
    __syncthreads();
    float inv = 1.0f / (s_red[0] + s_red[1] + s_red[2] + s_red[3]);
    wword[b * L_ + tid]       = p0 * inv;
    wword[b * L_ + tid + 256] = p1 * inv;
}

// ---------------------------------------------------------------------------
// K2: context accumulation. B*16 = 1024 blocks, 32 words each.
// Lane: h = word parity, j = float4 chunk. 2 words per wave-iter, no shuffles.
// ---------------------------------------------------------------------------
__global__ __launch_bounds__(256) void context_kernel(
    const int* __restrict__ inputs, const float* __restrict__ wword,
    const float* __restrict__ emb, float* __restrict__ context)
{
    const int b    = blockIdx.x >> 4;
    const int base = (blockIdx.x & 15) * 32;
    const int tid  = threadIdx.x;
    const int wave = tid >> 6, lane = tid & 63;
    const int h = lane >> 5, j = lane & 31;

    __shared__ float s_w[32];
    __shared__ float s_part[8][D_];

    if (tid < 32) s_w[tid] = wword[b * L_ + base + tid] * (1.0f / 3.0f);
    __syncthreads();

    const int* in_b = inputs + b * (L_ * S_);
    float4 c = make_float4(0.f, 0.f, 0.f, 0.f);

    for (int wp = wave; wp < 16; wp += 4) {
        const int lw = wp * 2 + h;
        const int l  = base + lw;
        const float w = s_w[lw];
        float4 m = make_float4(0.f, 0.f, 0.f, 0.f);
#pragma unroll
        for (int s = 0; s < S_; ++s) {
            int idx = in_b[l * S_ + s];
            if (idx != 0) {
                float4 e = ((const float4*)(emb + (long)idx * D_))[j];
                m.x += e.x; m.y += e.y; m.z += e.z; m.w += e.w;
            }
        }
        c.x += w * m.x; c.y += w * m.y; c.z += w * m.z; c.w += w * m.w;
    }
    ((float4*)s_part[wave * 2 + h])[j] = c;
    __syncthreads();
    if (tid < D_) {
        float acc = 0.f;
#pragma unroll
        for (int p = 0; p < 8; ++p) acc += s_part[p][tid];
        atomicAdd(&context[b * D_ + tid], acc);
    }
}

// ---------------------------------------------------------------------------
// K3: sense softmax + hidden. B*16 blocks, 32 words each. 2 words/wave-iter,
// 5-deep shuffle reduce within 32-lane halves, 6 independent chains for ILP.
// ---------------------------------------------------------------------------
__global__ __launch_bounds__(256) void sense_kernel(
    const int* __restrict__ inputs, const float* __restrict__ lwp,
    const float* __restrict__ context, const float* __restrict__ emb,
    float* __restrict__ hidden)
{
    const int b    = blockIdx.x >> 4;
    const int base = (blockIdx.x & 15) * 32;
    const int tid  = threadIdx.x;
    const int wave = tid >> 6, lane = tid & 63;
    const int h = lane >> 5, j = lane & 31;

    __shared__ float s_part[8][D_];

    const int* in_b = inputs + b * (L_ * S_);
    const float lwb = lwp[b];
    const float4 c4 = ((const float4*)(context + b * D_))[j];

    float4 hacc = make_float4(0.f, 0.f, 0.f, 0.f);

    for (int wp = wave; wp < 16; wp += 4) {
        const int l = base + wp * 2 + h;
        float4 e[S_]; int id[S_]; float sim[S_];
#pragma unroll
        for (int s = 0; s < S_; ++s) {
            id[s] = in_b[l * S_ + s];
            if (id[s] != 0) e[s] = ((const float4*)(emb + (long)id[s] * D_))[j];
            else e[s] = make_float4(0.f, 0.f, 0.f, 0.f);
            sim[s] = e[s].x * c4.x + e[s].y * c4.y + e[s].z * c4.z + e[s].w * c4.w;
        }
#pragma unroll
        for (int off = 16; off >= 1; off >>= 1) {
            sim[0] += __shfl_xor(sim[0], off, 64);
            sim[1] += __shfl_xor(sim[1], off, 64);
            sim[2] += __shfl_xor(sim[2], off, 64);
        }
        float mm = fmaxf(sim[0], fmaxf(sim[1], sim[2]));
        float e0 = expf(sim[0] - mm), e1 = expf(sim[1] - mm), e2 = expf(sim[2] - mm);
        float f = lwb / (e0 + e1 + e2);
        float w0 = (id[0] != 0) ? e0 * f : 0.f;
        float w1 = (id[1] != 0) ? e1 * f : 0.f;
        float w2 = (id[2] != 0) ? e2 * f : 0.f;
        hacc.x += w0 * e[0].x + w1 * e[1].x + w2 * e[2].x;
        hacc.y += w0 * e[0].y + w1 * e[1].y + w2 * e[2].y;
        hacc.z += w0 * e[0].z + w1 * e[1].z + w2 * e[2].z;
        hacc.w += w0 * e[0].w + w1 * e[1].w + w2 * e[2].w;
    }
    ((float4*)s_part[wave * 2 + h])[j] = hacc;
    __syncthreads();
    if (tid < D_) {
        float acc = 0.f;
#pragma unroll
        for (int p = 0; p < 8; ++p) acc += s_part[p][tid];
        atomicAdd(&hidden[b * D_ + tid], acc);
    }
}

// ---------------------------------------------------------------------------
// K4: logits via MFMA + fused per-(block,row) max/sumexp partials.
// 782 blocks x 4 waves; wave = 64 rows x 16 cols.
// ---------------------------------------------------------------------------
__global__ __launch_bounds__(256) void logits_kernel(
    const float* __restrict__ hidden, const float* __restrict__ Wl,
    const float* __restrict__ bl, float* __restrict__ logits,
    float* __restrict__ pM, float* __restrict__ pS)
{
    const int tid  = threadIdx.x;
    const int wave = tid >> 6, lane = tid & 63;
    const int m15  = lane & 15, quad = lane >> 4;
    const int v    = blockIdx.x * 64 + wave * 16 + m15;
    const bool valid = (v < OV_);
    const int vc   = valid ? v : (OV_ - 1);

    bf16x8 afrag[4][4];
#pragma unroll
    for (int t = 0; t < 4; ++t) {
        const float* hrow = hidden + (t * 16 + m15) * D_ + quad * 8;
#pragma unroll
        for (int ks = 0; ks < 4; ++ks) {
            float4 x0 = *(const float4*)(hrow + ks * 32);
            float4 x1 = *(const float4*)(hrow + ks * 32 + 4);
            bf16x8 a;
            a[0] = f2bf(x0.x); a[1] = f2bf(x0.y); a[2] = f2bf(x0.z); a[3] = f2bf(x0.w);
            a[4] = f2bf(x1.x); a[5] = f2bf(x1.y); a[6] = f2bf(x1.z); a[7] = f2bf(x1.w);
            afrag[t][ks] = a;
        }
    }

    f32x4 acc[4];
#pragma unroll
    for (int t = 0; t < 4; ++t) acc[t] = (f32x4){0.f, 0.f, 0.f, 0.f};

    const float* wrow = Wl + (long)vc * D_ + quad * 8;
#pragma unroll
    for (int ks = 0; ks < 4; ++ks) {
        float4 x0 = *(const float4*)(wrow + ks * 32);
        float4 x1 = *(const float4*)(wrow + ks * 32 + 4);
        bf16x8 bfr;
        bfr[0] = f2bf(x0.x); bfr[1] = f2bf(x0.y); bfr[2] = f2bf(x0.z); bfr[3] = f2bf(x0.w);
        bfr[4] = f2bf(x1.x); bfr[5] = f2bf(x1.y); bfr[6] = f2bf(x1.z); bfr[7] = f2bf(x1.w);
#pragma unroll
        for (int t = 0; t < 4; ++t)
            acc[t] = __builtin_amdgcn_mfma_f32_16x16x32_bf16(afrag[t][ks], bfr,
                                                             acc[t], 0, 0, 0);
    }

    const float bias = bl[vc];
    if (valid) {
#pragma unroll
        for (int t = 0; t < 4; ++t)
#pragma unroll
            for (int r = 0; r < 4; ++r) {
                const int row = t * 16 + quad * 4 + r;
                logits[(long)row * OV_ + v] = acc[t][r] + bias;
            }
    }

    // ---- fused partial max / sumexp over this block's 64 cols ----
    __shared__ float s_pm[64][4];
    __shared__ float s_ps[64][4];
#pragma unroll
    for (int t = 0; t < 4; ++t) {
#pragma unroll
        for (int r = 0; r < 4; ++r) {
            float x = valid ? acc[t][r] + bias : -INFINITY;
            float mx = x;
#pragma unroll
            for (int off = 8; off >= 1; off >>= 1)
                mx = fmaxf(mx, __shfl_xor(mx, off, 64));
            float se = valid ? expf(x - mx) : 0.f;
#pragma unroll
            for (int off = 8; off >= 1; off >>= 1) se += __shfl_xor(se, off, 64);
            if (m15 == 0) {
                const int row = t * 16 + quad * 4 + r;
                s_pm[row][wave] = mx;
                s_ps[row][wave] = se;
            }
        }
    }
    __syncthreads();
    if (tid < 64) {
        float m0 = s_pm[tid][0], m1 = s_pm[tid][1];
        float m2 = s_pm[tid][2], m3 = s_pm[tid][3];
        float m = fmaxf(fmaxf(m0, m1), fmaxf(m2, m3));
        float s = s_ps[tid][0] * expf(m0 - m) + s_ps[tid][1] * expf(m1 - m)
                + s_ps[tid][2] * expf(m2 - m) + s_ps[tid][3] * expf(m3 - m);
        pM[tid * NBLK_ + blockIdx.x] = m;
        pS[tid * NBLK_ + blockIdx.x] = s;
    }
}

// ---------------------------------------------------------------------------
// K5: logZ[b] = m + log(sum) from 782 partials per row. 64 blocks.
// ---------------------------------------------------------------------------
__global__ __launch_bounds__(256) void reducez_kernel(
    const float* __restrict__ pM, const float* __restrict__ pS,
    float* __restrict__ logZ)
{
    const int b = blockIdx.x;
    const int tid = threadIdx.x;
    const int wave = tid >> 6, lane = tid & 63;
    const float* rm = pM + b * NBLK_;
    const float* rs = pS + b * NBLK_;
    __shared__ float s_red[4];

    float m = -INFINITY;
    for (int i = tid; i < NBLK_; i += 256) m = fmaxf(m, rm[i]);
    m = waveReduceMax(m);
    if (lane == 0) s_red[wave] = m;
    __syncthreads();
    m = fmaxf(fmaxf(s_red[0], s_red[1]), fmaxf(s_red[2], s_red[3]));
    __syncthreads();

    float s = 0.f;
    for (int i = tid; i < NBLK_; i += 256) s += rs[i] * expf(rm[i] - m);
    s = waveReduceSum(s);
    if (lane == 0) s_red[wave] = s;
    __syncthreads();
    if (tid == 0)
        logZ[b] = m + logf(s_red[0] + s_red[1] + s_red[2] + s_red[3]);
}

// ---------------------------------------------------------------------------
// K6: out = logit - logZ[b]; float4, exact cover. 3125 blocks.
// ---------------------------------------------------------------------------
__global__ __launch_bounds__(256) void finalize_kernel(
    const float* __restrict__ logits, const float* __restrict__ logZ,
    float* __restrict__ out)
{
    const long i4 = (long)blockIdx.x * 256 + threadIdx.x;
    const long e  = i4 * 4;
    const int b = (int)(e / OV_);
    const float z = logZ[b];
    float4 x = ((const float4*)logits)[i4];
    x.x -= z; x.y -= z; x.z -= z; x.w -= z;
    ((float4*)out)[i4] = x;
}

extern "C" void kernel_launch(void* const* d_in, const int* in_sizes, int n_in,
                              void* d_out, int out_size, void* d_ws, size_t ws_size,
                              hipStream_t stream) {
    const int*   inputs = (const int*)d_in[0];
    const float* lw     = (const float*)d_in[1];
    const int*   mask   = (const int*)d_in[2];
    const float* emb    = (const float*)d_in[3];
    const float* Wa     = (const float*)d_in[4];
    const float* ba     = (const float*)d_in[5];
    const float* Wl     = (const float*)d_in[6];
    const float* bl     = (const float*)d_in[7];
    float* out = (float*)d_out;

    float* ws = (float*)d_ws;
    float* hidden  = ws;                          // 8,192
    float* logZ    = ws + 8192;                   // 64
    float* logits  = ws + 8256;                   // 3,200,000 (16B-aligned)
    float* P       = logits + (long)B_ * OV_;     // 100,000
    float* wword   = P + VOC_;                    // 32,768
    float* context = wword + B_ * L_;             // 8,192
    float* pM      = context + B_ * D_;           // 64*782 = 50,048
    float* pS      = pM + B_ * NBLK_;             // 50,048

    prequery_kernel<<<625, 256, 0, stream>>>(emb, Wa, P);
    wordsoftmax_kernel<<<B_, 256, 0, stream>>>(inputs, mask, P, ba, wword,
                                               context, hidden);
    context_kernel<<<B_ * 16, 256, 0, stream>>>(inputs, wword, emb, context);
    sense_kernel<<<B_ * 16, 256, 0, stream>>>(inputs, lw, context, emb, hidden);
    logits_kernel<<<NBLK_, 256, 0, stream>>>(hidden, Wl, bl, logits, pM, pS);
    reducez_kernel<<<B_, 256, 0, stream>>>(pM, pS, logZ);
    finalize_kernel<<<(B_ * OV_) / (4 * 256), 256, 0, stream>>>(logits, logZ, out);
}

// Round 5
// 161.046 us; speedup vs baseline: 4.6531x; 1.0915x over previous
//
#include <hip/hip_runtime.h>
#include <math.h>

#define B_    64
#define L_    512
#define S_    3
#define D_    128
#define OV_   50000
#define VOC_  100000
#define NBLK_ 782   // ceil(OV_/64)

typedef __attribute__((ext_vector_type(8))) short bf16x8;
typedef __attribute__((ext_vector_type(4))) float f32x4;

__device__ __forceinline__ float waveReduceSum(float v) {
#pragma unroll
    for (int off = 32; off >= 1; off >>= 1) v += __shfl_xor(v, off, 64);
    return v;
}
__device__ __forceinline__ float waveReduceMax(float v) {
#pragma unroll
    for (int off = 32; off >= 1; off >>= 1) v = fmaxf(v, __shfl_xor(v, off, 64));
    return v;
}

// fp32 -> bf16 round-to-nearest-even
__device__ __forceinline__ short f2bf(float f) {
    unsigned int u = __float_as_uint(f);
    return (short)((u + 0x7FFFu + ((u >> 16) & 1u)) >> 16);
}

// ---------------------------------------------------------------------------
// K0: P[v] = E[v] . W_attn (streamed). Also zeroes context/hidden (blocks<64).
// ---------------------------------------------------------------------------
__global__ __launch_bounds__(256) void prequery_kernel(
    const float* __restrict__ emb, const float* __restrict__ Wa,
    float* __restrict__ P, float* __restrict__ context,
    float* __restrict__ hidden)
{
    const int tid = threadIdx.x;
    if (blockIdx.x < 64 && tid < D_) {
        context[blockIdx.x * D_ + tid] = 0.f;
        hidden[blockIdx.x * D_ + tid]  = 0.f;
    }

    const int lane = tid & 63;
    const int q = lane >> 4;            // which of 4 rows
    const int j = lane & 15;            // float8 chunk of 128 dims
    const int waveg = blockIdx.x * 4 + (tid >> 6);
    const int nwaves = gridDim.x * 4;

    const float4 wa0 = ((const float4*)Wa)[2 * j];
    const float4 wa1 = ((const float4*)Wa)[2 * j + 1];

    for (int r0 = waveg * 4; r0 < VOC_; r0 += nwaves * 4) {
        const float4* row = (const float4*)(emb + (long)(r0 + q) * D_ + j * 8);
        float4 e0 = row[0], e1 = row[1];
        float s = e0.x * wa0.x + e0.y * wa0.y + e0.z * wa0.z + e0.w * wa0.w
                + e1.x * wa1.x + e1.y * wa1.y + e1.z * wa1.z + e1.w * wa1.w;
#pragma unroll
        for (int off = 8; off >= 1; off >>= 1) s += __shfl_xor(s, off, 64);
        if (j == 0) P[r0 + q] = s;
    }
}

// ---------------------------------------------------------------------------
// K1: fused word softmax (redundant per 16 sibling blocks, L2-hot) + context
// accumulation. B*16 = 1024 blocks, 32 words each.
// ---------------------------------------------------------------------------
__global__ __launch_bounds__(256) void context_kernel(
    const int* __restrict__ inputs, const int* __restrict__ mask,
    const float* __restrict__ P, const float* __restrict__ ba,
    const float* __restrict__ emb, float* __restrict__ context)
{
    const int b    = blockIdx.x >> 4;
    const int base = (blockIdx.x & 15) * 32;
    const int tid  = threadIdx.x;
    const int wave = tid >> 6, lane = tid & 63;
    const int h = lane >> 5, j = lane & 31;

    __shared__ float s_imp[L_];
    __shared__ float s_red[4];
    __shared__ float s_part[8][D_];

    const int* in_b = inputs + b * (L_ * S_);
    const float babias = ba[0];

    // ---- word_imp for all 512 words of this b ----
#pragma unroll
    for (int half = 0; half < 2; ++half) {
        const int l = tid + half * 256;
        float acc = 0.f;
#pragma unroll
        for (int s = 0; s < S_; ++s) {
            int idx = in_b[l * S_ + s];
            if (idx != 0) acc += P[idx];
        }
        float imp = acc * (1.0f / 3.0f) + babias;
        s_imp[l] = mask[b * L_ + l] ? -INFINITY : imp;
    }
    __syncthreads();

    // ---- softmax over 512 words ----
    float v0 = s_imp[tid], v1 = s_imp[tid + 256];
    float m = waveReduceMax(fmaxf(v0, v1));
    if (lane == 0) s_red[wave] = m;
    __syncthreads();
    m = fmaxf(fmaxf(s_red[0], s_red[1]), fmaxf(s_red[2], s_red[3]));
    __syncthreads();
    float p0 = expf(v0 - m), p1 = expf(v1 - m);
    float ssum = waveReduceSum(p0 + p1);
    if (lane == 0) s_red[wave] = ssum;
    __syncthreads();
    float inv = (1.0f / 3.0f) / (s_red[0] + s_red[1] + s_red[2] + s_red[3]);
    s_imp[tid]       = p0 * inv;
    s_imp[tid + 256] = p1 * inv;
    __syncthreads();

    // ---- gather + weighted accumulate over this block's 32 words ----
    float4 c = make_float4(0.f, 0.f, 0.f, 0.f);
    for (int wp = wave; wp < 16; wp += 4) {
        const int l = base + wp * 2 + h;
        const float w = s_imp[l];
        float4 mm = make_float4(0.f, 0.f, 0.f, 0.f);
#pragma unroll
        for (int s = 0; s < S_; ++s) {
            int idx = in_b[l * S_ + s];
            if (idx != 0) {
                float4 e = ((const float4*)(emb + (long)idx * D_))[j];
                mm.x += e.x; mm.y += e.y; mm.z += e.z; mm.w += e.w;
            }
        }
        c.x += w * mm.x; c.y += w * mm.y; c.z += w * mm.z; c.w += w * mm.w;
    }
    ((float4*)s_part[wave * 2 + h])[j] = c;
    __syncthreads();
    if (tid < D_) {
        float acc = 0.f;
#pragma unroll
        for (int p = 0; p < 8; ++p) acc += s_part[p][tid];
        atomicAdd(&context[b * D_ + tid], acc);
    }
}

// ---------------------------------------------------------------------------
// K2: sense softmax + hidden. B*16 blocks, 32 words each. No-max 3-way
// softmax (sims are tiny), 5-deep shuffle reduce in 32-lane halves.
// ---------------------------------------------------------------------------
__global__ __launch_bounds__(256) void sense_kernel(
    const int* __restrict__ inputs, const float* __restrict__ lwp,
    const float* __restrict__ context, const float* __restrict__ emb,
    float* __restrict__ hidden)
{
    const int b    = blockIdx.x >> 4;
    const int base = (blockIdx.x & 15) * 32;
    const int tid  = threadIdx.x;
    const int wave = tid >> 6, lane = tid & 63;
    const int h = lane >> 5, j = lane & 31;

    __shared__ float s_part[8][D_];

    const int* in_b = inputs + b * (L_ * S_);
    const float lwb = lwp[b];
    const float4 c4 = ((const float4*)(context + b * D_))[j];

    float4 hacc = make_float4(0.f, 0.f, 0.f, 0.f);

    for (int wp = wave; wp < 16; wp += 4) {
        const int l = base + wp * 2 + h;
        float4 e[S_]; int id[S_]; float sim[S_];
#pragma unroll
        for (int s = 0; s < S_; ++s) {
            id[s] = in_b[l * S_ + s];
            if (id[s] != 0) e[s] = ((const float4*)(emb + (long)id[s] * D_))[j];
            else e[s] = make_float4(0.f, 0.f, 0.f, 0.f);
            sim[s] = e[s].x * c4.x + e[s].y * c4.y + e[s].z * c4.z + e[s].w * c4.w;
        }
#pragma unroll
        for (int off = 16; off >= 1; off >>= 1) {
            sim[0] += __shfl_xor(sim[0], off, 64);
            sim[1] += __shfl_xor(sim[1], off, 64);
            sim[2] += __shfl_xor(sim[2], off, 64);
        }
        float e0 = expf(sim[0]), e1 = expf(sim[1]), e2 = expf(sim[2]);
        float f = lwb / (e0 + e1 + e2);
        float w0 = (id[0] != 0) ? e0 * f : 0.f;
        float w1 = (id[1] != 0) ? e1 * f : 0.f;
        float w2 = (id[2] != 0) ? e2 * f : 0.f;
        hacc.x += w0 * e[0].x + w1 * e[1].x + w2 * e[2].x;
        hacc.y += w0 * e[0].y + w1 * e[1].y + w2 * e[2].y;
        hacc.z += w0 * e[0].z + w1 * e[1].z + w2 * e[2].z;
        hacc.w += w0 * e[0].w + w1 * e[1].w + w2 * e[2].w;
    }
    ((float4*)s_part[wave * 2 + h])[j] = hacc;
    __syncthreads();
    if (tid < D_) {
        float acc = 0.f;
#pragma unroll
        for (int p = 0; p < 8; ++p) acc += s_part[p][tid];
        atomicAdd(&hidden[b * D_ + tid], acc);
    }
}

// ---------------------------------------------------------------------------
// K3: logits via MFMA. hidden staged once per block as bf16 in LDS
// (row-padded +8 shorts for bank-conflict-freedom). No-max sumexp epilogue
// (logits are O(1): exp cannot overflow; logsumexp is shift-invariant).
// ---------------------------------------------------------------------------
__global__ __launch_bounds__(256) void logits_kernel(
    const float* __restrict__ hidden, const float* __restrict__ Wl,
    const float* __restrict__ bl, float* __restrict__ logits,
    float* __restrict__ pS)
{
    __shared__ short s_hbf[64][136];   // 64 rows x 128 bf16, +8 pad
    const int tid  = threadIdx.x;
    const int wave = tid >> 6, lane = tid & 63;
    const int m15  = lane & 15, quad = lane >> 4;
    const int v    = blockIdx.x * 64 + wave * 16 + m15;
    const bool valid = (v < OV_);
    const int vc   = valid ? v : (OV_ - 1);

    // stage hidden -> bf16 LDS (8192 values, 32 per thread)
    for (int i = tid; i < 2048; i += 256) {          // float4 index
        float4 x = ((const float4*)hidden)[i];
        const int r = i >> 5;
        const int c = (i & 31) * 4;
        short* dst = &s_hbf[r][c];
        dst[0] = f2bf(x.x); dst[1] = f2bf(x.y);
        dst[2] = f2bf(x.z); dst[3] = f2bf(x.w);
    }
    __syncthreads();

    f32x4 acc[4];
#pragma unroll
    for (int t = 0; t < 4; ++t) acc[t] = (f32x4){0.f, 0.f, 0.f, 0.f};

    const float* wrow = Wl + (long)vc * D_ + quad * 8;
#pragma unroll
    for (int ks = 0; ks < 4; ++ks) {
        float4 x0 = *(const float4*)(wrow + ks * 32);
        float4 x1 = *(const float4*)(wrow + ks * 32 + 4);
        bf16x8 bfr;
        bfr[0] = f2bf(x0.x); bfr[1] = f2bf(x0.y); bfr[2] = f2bf(x0.z); bfr[3] = f2bf(x0.w);
        bfr[4] = f2bf(x1.x); bfr[5] = f2bf(x1.y); bfr[6] = f2bf(x1.z); bfr[7] = f2bf(x1.w);
#pragma unroll
        for (int t = 0; t < 4; ++t) {
            bf16x8 afr = *(const bf16x8*)&s_hbf[t * 16 + m15][ks * 32 + quad * 8];
            acc[t] = __builtin_amdgcn_mfma_f32_16x16x32_bf16(afr, bfr,
                                                             acc[t], 0, 0, 0);
        }
    }

    const float bias = bl[vc];
    if (valid) {
#pragma unroll
        for (int t = 0; t < 4; ++t)
#pragma unroll
            for (int r = 0; r < 4; ++r) {
                const int row = t * 16 + quad * 4 + r;
                logits[(long)row * OV_ + v] = acc[t][r] + bias;
            }
    }

    // ---- partial sumexp (no shift) over this block's 64 cols ----
    __shared__ float s_ps[64][4];
#pragma unroll
    for (int t = 0; t < 4; ++t) {
#pragma unroll
        for (int r = 0; r < 4; ++r) {
            float se = valid ? expf(acc[t][r] + bias) : 0.f;
#pragma unroll
            for (int off = 8; off >= 1; off >>= 1) se += __shfl_xor(se, off, 64);
            if (m15 == 0) s_ps[t * 16 + quad * 4 + r][wave] = se;
        }
    }
    __syncthreads();
    if (tid < 64)
        pS[tid * NBLK_ + blockIdx.x] = s_ps[tid][0] + s_ps[tid][1]
                                     + s_ps[tid][2] + s_ps[tid][3];
}

// ---------------------------------------------------------------------------
// K4: logZ[b] = log(sum of partials). 64 blocks.
// ---------------------------------------------------------------------------
__global__ __launch_bounds__(256) void reducez_kernel(
    const float* __restrict__ pS, float* __restrict__ logZ)
{
    const int b = blockIdx.x;
    const int tid = threadIdx.x;
    const int wave = tid >> 6, lane = tid & 63;
    const float* rs = pS + b * NBLK_;
    __shared__ float s_red[4];

    float s = 0.f;
    for (int i = tid; i < NBLK_; i += 256) s += rs[i];
    s = waveReduceSum(s);
    if (lane == 0) s_red[wave] = s;
    __syncthreads();
    if (tid == 0)
        logZ[b] = logf(s_red[0] + s_red[1] + s_red[2] + s_red[3]);
}

// ---------------------------------------------------------------------------
// K5: out = logit - logZ[b]; float4, exact cover. 3125 blocks.
// ---------------------------------------------------------------------------
__global__ __launch_bounds__(256) void finalize_kernel(
    const float* __restrict__ logits, const float* __restrict__ logZ,
    float* __restrict__ out)
{
    const long i4 = (long)blockIdx.x * 256 + threadIdx.x;
    const long e  = i4 * 4;
    const int b = (int)(e / OV_);
    const float z = logZ[b];
    float4 x = ((const float4*)logits)[i4];
    x.x -= z; x.y -= z; x.z -= z; x.w -= z;
    ((float4*)out)[i4] = x;
}

extern "C" void kernel_launch(void* const* d_in, const int* in_sizes, int n_in,
                              void* d_out, int out_size, void* d_ws, size_t ws_size,
                              hipStream_t stream) {
    const int*   inputs = (const int*)d_in[0];
    const float* lw     = (const float*)d_in[1];
    const int*   mask   = (const int*)d_in[2];
    const float* emb    = (const float*)d_in[3];
    const float* Wa     = (const float*)d_in[4];
    const float* ba     = (const float*)d_in[5];
    const float* Wl     = (const float*)d_in[6];
    const float* bl     = (const float*)d_in[7];
    float* out = (float*)d_out;

    float* ws = (float*)d_ws;
    float* hidden  = ws;                          // 8,192
    float* logZ    = ws + 8192;                   // 64
    float* logits  = ws + 8256;                   // 3,200,000 (16B-aligned)
    float* P       = logits + (long)B_ * OV_;     // 100,000
    float* context = P + VOC_;                    // 8,192
    float* pS      = context + B_ * D_;           // 64*782 = 50,048

    prequery_kernel<<<625, 256, 0, stream>>>(emb, Wa, P, context, hidden);
    context_kernel<<<B_ * 16, 256, 0, stream>>>(inputs, mask, P, ba, emb, context);
    sense_kernel<<<B_ * 16, 256, 0, stream>>>(inputs, lw, context, emb, hidden);
    logits_kernel<<<NBLK_, 256, 0, stream>>>(hidden, Wl, bl, logits, pS);
    reducez_kernel<<<B_, 256, 0, stream>>>(pS, logZ);
    finalize_kernel<<<(B_ * OV_) / (4 * 256), 256, 0, stream>>>(logits, logZ, out);
}